// Round 8
// baseline (173.783 us; speedup 1.0000x reference)
//
#include <hip/hip_runtime.h>

#define HW      (1024 * 1024)
#define HW4     (HW / 4)
#define NBINS   4096
#define NIMG    9                 // 8 input images + 1 style
#define BPI     128               // 1152 hist blocks
#define THREADS 256
#define F4_PER_BLOCK (HW4 / BPI)  // 2048 float4 per block per channel
#define NSTAGE  (F4_PER_BLOCK / (2 * THREADS))  // 4 pipeline stages
#define RBINS   16                // bins per reduce block -> 256 reduce blocks
#define RBLOCKS (NBINS / RBINS)

typedef float f4 __attribute__((ext_vector_type(4)));

// Exact searchsorted(boundaries, x, 'left'), boundaries b_j = (j+1)/8 - 1.
// Branchless binary search, exact float compares (verified absmax 0.0 R1-R7).
__device__ __forceinline__ int bin16(float x) {
    int lo = 0;
    if (0.0f < x) lo = 8;
    if ((float)(lo + 4) * 0.125f - 1.0f < x) lo += 4;
    if ((float)(lo + 2) * 0.125f - 1.0f < x) lo += 2;
    if ((float)(lo + 1) * 0.125f - 1.0f < x) lo += 1;
    return lo;
}

__device__ __forceinline__ int bin3(float r, float g, float b) {
    return bin16(r) + 16 * bin16(g) + 256 * bin16(b);
}

__device__ __forceinline__ void acc4(int* lh, f4 r, f4 g, f4 b) {
    atomicAdd(&lh[bin3(r.x, g.x, b.x)], 1);
    atomicAdd(&lh[bin3(r.y, g.y, b.y)], 1);
    atomicAdd(&lh[bin3(r.z, g.z, b.z)], 1);
    atomicAdd(&lh[bin3(r.w, g.w, b.w)], 1);
}

// Per-block LDS histogram, depth-2 software pipeline (R6 config = best known).
// Block (0,0) also zero-inits the sum/ctr cells consumed by the next kernel
// (kernel-boundary release makes plain stores visible -- same mechanism the
// u16 partials rely on).
__global__ __launch_bounds__(THREADS, 4) void hist_kernel(
        const float* __restrict__ input,        // [8,3,HW]
        const float* __restrict__ style,        // [1,3,HW]
        unsigned short* __restrict__ part,      // [NIMG][BPI][NBINS] u16
        int* __restrict__ sumctr) {             // [2]: {sum, ctr}
    __shared__ int lh[NBINS];                   // 16 KB
    const int img = blockIdx.y;
    const int blk = blockIdx.x;
    const float* base = (img < 8) ? (input + (size_t)img * 3 * HW) : style;

    if (img == 0 && blk == 0 && threadIdx.x == 0) {
        sumctr[0] = 0;
        sumctr[1] = 0;
    }

    for (int i = threadIdx.x; i < NBINS; i += THREADS) lh[i] = 0;
    __syncthreads();

    const f4* c0 = (const f4*)(base);
    const f4* c1 = (const f4*)(base + HW);
    const f4* c2 = (const f4*)(base + 2 * HW);
    const int start = blk * F4_PER_BLOCK + threadIdx.x;

    f4 buf[2][6];
    auto load_stage = [&](int s, f4* d) {
        const int p0 = start + s * 2 * THREADS;
        const int p1 = p0 + THREADS;
        d[0] = c0[p0]; d[1] = c1[p0]; d[2] = c2[p0];
        d[3] = c0[p1]; d[4] = c1[p1]; d[5] = c2[p1];
    };

    load_stage(0, buf[0]);
#pragma unroll
    for (int s = 0; s < NSTAGE; ++s) {
        if (s + 1 < NSTAGE) load_stage(s + 1, buf[(s + 1) & 1]);
        f4* d = buf[s & 1];
        acc4(lh, d[0], d[1], d[2]);
        acc4(lh, d[3], d[4], d[5]);
    }
    __syncthreads();

    // Flush: pack 8 counts -> uint4 (16 B/thread/iter), 2 iters.
    uint4* dst = (uint4*)(part + ((size_t)img * BPI + blk) * NBINS);
    for (int i = threadIdx.x; i < NBINS / 8; i += THREADS) {
        uint4 v;
        v.x = (unsigned)lh[8 * i]     | ((unsigned)lh[8 * i + 1] << 16);
        v.y = (unsigned)lh[8 * i + 2] | ((unsigned)lh[8 * i + 3] << 16);
        v.z = (unsigned)lh[8 * i + 4] | ((unsigned)lh[8 * i + 5] << 16);
        v.w = (unsigned)lh[8 * i + 6] | ((unsigned)lh[8 * i + 7] << 16);
        dst[i] = v;
    }
}

// Fused reduce + |diff| + global finish. Block b owns bins [16b, 16b+16):
// sums 128 u16 partials per bin per image (style first -> target in LDS),
// accumulates |H - tgt|, then:
//   relaxed fetch_add(sum, acc); release fetch_add(ctr, 1);
// the block seeing prev == RBLOCKS-1 loads the final sum (RMW release chain
// -> acquire gives visibility of all 256 adds) and writes the scalar loss.
__global__ __launch_bounds__(THREADS) void reduce_loss_kernel(
        const unsigned short* __restrict__ part,  // [NIMG][BPI][NBINS]
        int* __restrict__ sumctr,                 // [2]: {sum, ctr}
        float* __restrict__ out) {
    __shared__ int red[16][RBINS];
    __shared__ int tgt[RBINS];
    const int b0   = blockIdx.x * RBINS;
    const int lane = threadIdx.x & 15;   // bin within chunk
    const int pg   = threadIdx.x >> 4;   // partial-group 0..15
    int acc = 0;

    for (int step = 0; step < NIMG; ++step) {
        const int img = (step == 0) ? 8 : step - 1;   // style first
        const unsigned short* p =
            part + ((size_t)img * BPI + pg) * NBINS + b0 + lane;
        int s = 0;
#pragma unroll 8
        for (int k = 0; k < BPI / 16; ++k)
            s += p[(size_t)(16 * k) * NBINS];
        red[pg][lane] = s;
        __syncthreads();
        if (threadIdx.x < RBINS) {
            int tot = 0;
#pragma unroll
            for (int r = 0; r < 16; ++r) tot += red[r][threadIdx.x];
            if (step == 0) {
                tgt[threadIdx.x] = tot;
            } else {
                const int d = tot - tgt[threadIdx.x];
                acc += (d < 0) ? -d : d;
            }
        }
        __syncthreads();   // guard red[] reuse
    }

    // acc lives in threads 0..15 (wave 0); other lanes hold 0.
    for (int off = 32; off; off >>= 1) acc += __shfl_down(acc, off, 64);
    if (threadIdx.x == 0) {
        __hip_atomic_fetch_add(&sumctr[0], acc, __ATOMIC_RELAXED,
                               __HIP_MEMORY_SCOPE_AGENT);
        const int prev = __hip_atomic_fetch_add(&sumctr[1], 1, __ATOMIC_ACQ_REL,
                                                __HIP_MEMORY_SCOPE_AGENT);
        if (prev == RBLOCKS - 1) {
            const int t = __hip_atomic_load(&sumctr[0], __ATOMIC_RELAXED,
                                            __HIP_MEMORY_SCOPE_AGENT);
            // divide by HW * 8 * NBINS = 2^35 (integer-exact, t <= 16.8M)
            out[0] = (float)((double)t / 34359738368.0);
        }
    }
}

extern "C" void kernel_launch(void* const* d_in, const int* in_sizes, int n_in,
                              void* d_out, int out_size, void* d_ws, size_t ws_size,
                              hipStream_t stream) {
    const float* input = (const float*)d_in[0];  // [8,3,1024,1024]
    const float* style = (const float*)d_in[1];  // [1,3,1024,1024]
    unsigned short* part = (unsigned short*)d_ws;   // 9*128*4096 u16 = 9.44 MB
    int* sumctr = (int*)((char*)d_ws +
                         (size_t)NIMG * BPI * NBINS * sizeof(unsigned short));

    hipLaunchKernelGGL(hist_kernel, dim3(BPI, NIMG), dim3(THREADS), 0, stream,
                       input, style, part, sumctr);
    hipLaunchKernelGGL(reduce_loss_kernel, dim3(RBLOCKS), dim3(THREADS),
                       0, stream, part, sumctr, (float*)d_out);
}

// Round 9
// 170.565 us; speedup vs baseline: 1.0189x; 1.0189x over previous
//
#include <hip/hip_runtime.h>

#define HW      (1024 * 1024)
#define HW4     (HW / 4)
#define NBINS   4096
#define NIMG    9                 // 8 input images + 1 style
#define BPI     128               // 1152 hist blocks, 4.5/CU
#define THREADS 256
#define F4_PER_BLOCK (HW4 / BPI)  // 2048 float4 per block per channel
#define NSTAGE  (F4_PER_BLOCK / (2 * THREADS))  // 4 pipeline stages
#define RBINS   16                // bins per reduce block -> 256 reduce blocks

typedef float f4 __attribute__((ext_vector_type(4)));

// Exact searchsorted(boundaries, x, 'left'), boundaries b_j = (j+1)/8 - 1.
// Branchless binary search, exact float compares (verified absmax 0.0 R1-R8).
__device__ __forceinline__ int bin16(float x) {
    int lo = 0;
    if (0.0f < x) lo = 8;
    if ((float)(lo + 4) * 0.125f - 1.0f < x) lo += 4;
    if ((float)(lo + 2) * 0.125f - 1.0f < x) lo += 2;
    if ((float)(lo + 1) * 0.125f - 1.0f < x) lo += 1;
    return lo;
}

__device__ __forceinline__ int bin3(float r, float g, float b) {
    return bin16(r) + 16 * bin16(g) + 256 * bin16(b);
}

__device__ __forceinline__ void acc4(int* lh, f4 r, f4 g, f4 b) {
    atomicAdd(&lh[bin3(r.x, g.x, b.x)], 1);
    atomicAdd(&lh[bin3(r.y, g.y, b.y)], 1);
    atomicAdd(&lh[bin3(r.z, g.z, b.z)], 1);
    atomicAdd(&lh[bin3(r.w, g.w, b.w)], 1);
}

// Per-block LDS histogram, depth-3 software pipeline: 12 float4 loads in
// flight while consuming a stage (Little's law: ~3 KB/CU in flight at
// ~300 cyc latency -> ~6 TB/s). launch_bounds(256,4) keeps the 128-VGPR
// budget (depth-3 needs ~100 VGPR; a tighter cap serialized it in R7).
__global__ __launch_bounds__(THREADS, 4) void hist_kernel(
        const float* __restrict__ input,        // [8,3,HW]
        const float* __restrict__ style,        // [1,3,HW]
        unsigned short* __restrict__ part) {    // [NIMG][BPI][NBINS] u16
    __shared__ int lh[NBINS];                   // 16 KB
    const int img = blockIdx.y;
    const int blk = blockIdx.x;
    const float* base = (img < 8) ? (input + (size_t)img * 3 * HW) : style;

    for (int i = threadIdx.x; i < NBINS; i += THREADS) lh[i] = 0;
    __syncthreads();

    const f4* c0 = (const f4*)(base);
    const f4* c1 = (const f4*)(base + HW);
    const f4* c2 = (const f4*)(base + 2 * HW);
    const int start = blk * F4_PER_BLOCK + threadIdx.x;

    f4 buf[3][6];
    auto load_stage = [&](int s, f4* d) {
        const int p0 = start + s * 2 * THREADS;
        const int p1 = p0 + THREADS;
        d[0] = c0[p0]; d[1] = c1[p0]; d[2] = c2[p0];
        d[3] = c0[p1]; d[4] = c1[p1]; d[5] = c2[p1];
    };

    load_stage(0, buf[0]);
    load_stage(1, buf[1]);
#pragma unroll
    for (int s = 0; s < NSTAGE; ++s) {
        if (s + 2 < NSTAGE) load_stage(s + 2, buf[(s + 2) % 3]);
        f4* d = buf[s % 3];
        acc4(lh, d[0], d[1], d[2]);
        acc4(lh, d[3], d[4], d[5]);
    }
    __syncthreads();

    // Flush: pack 8 counts -> uint4 (16 B/thread/iter), 2 iters.
    uint4* dst = (uint4*)(part + ((size_t)img * BPI + blk) * NBINS);
    for (int i = threadIdx.x; i < NBINS / 8; i += THREADS) {
        uint4 v;
        v.x = (unsigned)lh[8 * i]     | ((unsigned)lh[8 * i + 1] << 16);
        v.y = (unsigned)lh[8 * i + 2] | ((unsigned)lh[8 * i + 3] << 16);
        v.z = (unsigned)lh[8 * i + 4] | ((unsigned)lh[8 * i + 5] << 16);
        v.w = (unsigned)lh[8 * i + 6] | ((unsigned)lh[8 * i + 7] << 16);
        dst[i] = v;
    }
}

// Fused reduce + per-bin |diff|: block b owns bins [16b, 16b+16). For each
// image, sum its 128 u16 partials per bin (style first -> target in LDS),
// accumulate |H - tgt| and plain-store one int per block. No atomics.
__global__ __launch_bounds__(THREADS) void reduce_loss_kernel(
        const unsigned short* __restrict__ part,  // [NIMG][BPI][NBINS]
        int* __restrict__ slots) {                // [256]
    __shared__ int red[16][RBINS];
    __shared__ int tgt[RBINS];
    const int b0   = blockIdx.x * RBINS;
    const int lane = threadIdx.x & 15;   // bin within chunk
    const int pg   = threadIdx.x >> 4;   // partial-group 0..15
    int acc = 0;

    for (int step = 0; step < NIMG; ++step) {
        const int img = (step == 0) ? 8 : step - 1;   // style first
        const unsigned short* p =
            part + ((size_t)img * BPI + pg) * NBINS + b0 + lane;
        int s = 0;
#pragma unroll 8
        for (int k = 0; k < BPI / 16; ++k)
            s += p[(size_t)(16 * k) * NBINS];
        red[pg][lane] = s;
        __syncthreads();
        if (threadIdx.x < RBINS) {
            int tot = 0;
#pragma unroll
            for (int r = 0; r < 16; ++r) tot += red[r][threadIdx.x];
            if (step == 0) {
                tgt[threadIdx.x] = tot;
            } else {
                const int d = tot - tgt[threadIdx.x];
                acc += (d < 0) ? -d : d;
            }
        }
        __syncthreads();   // guard red[] reuse
    }

    // acc lives in threads 0..15 (wave 0); other lanes hold 0.
    for (int off = 32; off; off >>= 1) acc += __shfl_down(acc, off, 64);
    if (threadIdx.x == 0) slots[blockIdx.x] = acc;
}

// 1 wave: sum 256 slots, scale by 1/2^35 (integer-exact, sum <= 16.8M).
__global__ __launch_bounds__(64) void final_kernel(
        const int* __restrict__ slots, float* __restrict__ out) {
    const int t = threadIdx.x;
    int s = slots[t] + slots[t + 64] + slots[t + 128] + slots[t + 192];
    for (int off = 32; off; off >>= 1) s += __shfl_down(s, off, 64);
    if (t == 0) out[0] = (float)((double)s / 34359738368.0);
}

extern "C" void kernel_launch(void* const* d_in, const int* in_sizes, int n_in,
                              void* d_out, int out_size, void* d_ws, size_t ws_size,
                              hipStream_t stream) {
    const float* input = (const float*)d_in[0];  // [8,3,1024,1024]
    const float* style = (const float*)d_in[1];  // [1,3,1024,1024]
    unsigned short* part = (unsigned short*)d_ws;   // 9*128*4096 u16 = 9.44 MB
    int* slots = (int*)((char*)d_ws +
                        (size_t)NIMG * BPI * NBINS * sizeof(unsigned short));

    hipLaunchKernelGGL(hist_kernel, dim3(BPI, NIMG), dim3(THREADS), 0, stream,
                       input, style, part);
    hipLaunchKernelGGL(reduce_loss_kernel, dim3(NBINS / RBINS), dim3(THREADS),
                       0, stream, part, slots);
    hipLaunchKernelGGL(final_kernel, dim3(1), dim3(64), 0, stream,
                       slots, (float*)d_out);
}